// Round 1
// baseline (975.005 us; speedup 1.0000x reference)
//
#include <hip/hip_runtime.h>
#include <math.h>

#define LEAKY 0.2f

// ---------------- GEMM1: h1 = x @ W1  (N x 128 @ 128 x 128), fused a_src/a_dst dots ----------------
__global__ __launch_bounds__(256) void k_gemm1(
    const float* __restrict__ x, const float* __restrict__ W,
    const float* __restrict__ att_s, const float* __restrict__ att_d,
    float* __restrict__ h1, float* __restrict__ a1s, float* __restrict__ a1d, int N)
{
  __shared__ float Wl[128][128];   // 64 KB
  __shared__ float Xl[32][128];    // 16 KB
  int t = threadIdx.x;
  const float4* W4 = (const float4*)W;
  float4* Wl4 = (float4*)&Wl[0][0];
#pragma unroll
  for (int i = 0; i < 16; ++i) Wl4[t + i * 256] = W4[t + i * 256];
  int row0 = blockIdx.x * 32;
  const float4* X4 = (const float4*)x;
  float4* Xl4 = (float4*)&Xl[0][0];
#pragma unroll
  for (int i = 0; i < 4; ++i) {
    int id = t + i * 256;
    int r = id >> 5, c = id & 31;
    int gr = row0 + r;
    Xl4[id] = (gr < N) ? X4[(size_t)gr * 32 + c] : make_float4(0.f, 0.f, 0.f, 0.f);
  }
  __syncthreads();
  int cg = t & 31, rg = t >> 5;   // cols cg*4..+3, rows rg*4..+3
  float acc[4][4] = {};
  for (int k = 0; k < 128; k += 4) {
    float4 xv[4];
#pragma unroll
    for (int r = 0; r < 4; ++r) xv[r] = *(const float4*)&Xl[rg * 4 + r][k];
#pragma unroll
    for (int kk = 0; kk < 4; ++kk) {
      float4 wv = *(const float4*)&Wl[k + kk][cg * 4];
#pragma unroll
      for (int r = 0; r < 4; ++r) {
        float xs = (&xv[r].x)[kk];
        acc[r][0] = fmaf(xs, wv.x, acc[r][0]);
        acc[r][1] = fmaf(xs, wv.y, acc[r][1]);
        acc[r][2] = fmaf(xs, wv.z, acc[r][2]);
        acc[r][3] = fmaf(xs, wv.w, acc[r][3]);
      }
    }
  }
  int col = cg * 4;
  int h = col >> 6;             // head index (0/1); att layout [2,64] flat => att[col]
  float4 asv = *(const float4*)&att_s[col];
  float4 adv = *(const float4*)&att_d[col];
#pragma unroll
  for (int r = 0; r < 4; ++r) {
    int gr = row0 + rg * 4 + r;
    if (gr < N) {
      *(float4*)&h1[(size_t)gr * 128 + col] =
          make_float4(acc[r][0], acc[r][1], acc[r][2], acc[r][3]);
      float ps = acc[r][0] * asv.x + acc[r][1] * asv.y + acc[r][2] * asv.z + acc[r][3] * asv.w;
      float pd = acc[r][0] * adv.x + acc[r][1] * adv.y + acc[r][2] * adv.z + acc[r][3] * adv.w;
      atomicAdd(&a1s[gr * 2 + h], ps);
      atomicAdd(&a1d[gr * 2 + h], pd);
    }
  }
}

// ---------------- Edge pass layer 1: one wave per edge, 2 heads x 64 feats ----------------
__global__ __launch_bounds__(256) void k_edge1(
    const int* __restrict__ ei, const float* __restrict__ h1,
    const float* __restrict__ a1s, const float* __restrict__ a1d,
    float* __restrict__ s1, float* __restrict__ num1, int E, int Etot)
{
  int wid = (int)((blockIdx.x * 256 + threadIdx.x) >> 6);
  int lane = threadIdx.x & 63;
  if (wid >= Etot) return;
  int s, d;
  if (wid < E) { s = ei[wid]; d = ei[E + wid]; }
  else { s = d = wid - E; }
  float al0 = a1s[s * 2] + a1d[d * 2];
  float al1 = a1s[s * 2 + 1] + a1d[d * 2 + 1];
  al0 = (al0 > 0.f) ? al0 : LEAKY * al0;
  al1 = (al1 > 0.f) ? al1 : LEAKY * al1;
  float e0 = __expf(al0), e1 = __expf(al1);
  if (lane == 0) atomicAdd(&s1[d * 2], e0);
  if (lane == 1) atomicAdd(&s1[d * 2 + 1], e1);
  float v0 = h1[(size_t)s * 128 + lane];
  float v1 = h1[(size_t)s * 128 + 64 + lane];
  atomicAdd(&num1[(size_t)d * 128 + lane], e0 * v0);
  atomicAdd(&num1[(size_t)d * 128 + 64 + lane], e1 * v1);
}

// ---------------- Finalize layer 1: v = num/s + bias (in place), accumulate BN stats ----------------
__global__ __launch_bounds__(256) void k_fin1(
    float* __restrict__ num1, const float* __restrict__ s1,
    const float* __restrict__ b1, float* __restrict__ stats, int N)
{
  int t = threadIdx.x;
  int f = t & 127;
  int rg = t >> 7;    // 0..1
  int row0 = blockIdx.x * 128;
  int h = f >> 6;
  float bias = b1[f];
  float sum = 0.f, sq = 0.f;
  for (int r = rg; r < 128; r += 2) {
    int gr = row0 + r;
    if (gr >= N) break;
    float v = num1[(size_t)gr * 128 + f] / (s1[gr * 2 + h] + 1e-16f) + bias;
    num1[(size_t)gr * 128 + f] = v;
    sum += v; sq += v * v;
  }
  __shared__ float ls[256], lq[256];
  ls[t] = sum; lq[t] = sq;
  __syncthreads();
  if (t < 128) {
    sum = ls[t] + ls[t + 128];
    sq  = lq[t] + lq[t + 128];
    atomicAdd(&stats[f], sum);
    atomicAdd(&stats[128 + f], sq);
  }
}

// ---------------- BN params: k = g*rsqrt(var+eps); shift = be - mu*k ----------------
__global__ void k_bnp(const float* __restrict__ stats, const float* __restrict__ g,
                      const float* __restrict__ be, float* __restrict__ bnc, int N, int F)
{
  int f = threadIdx.x;
  if (f < F) {
    float mu = stats[f] / (float)N;
    float var = stats[F + f] / (float)N - mu * mu;
    float k = g[f] * rsqrtf(var + 1e-5f);
    bnc[f] = k;
    bnc[F + f] = be[f] - mu * k;
  }
}

// ---------------- GEMM2: h2 = relu(bn(v1)) @ W2  (N x 128 @ 128 x 64), fused a2 dots ----------------
__global__ __launch_bounds__(256) void k_gemm2(
    const float* __restrict__ v1, const float* __restrict__ W2,
    const float* __restrict__ bnc1,
    const float* __restrict__ att_s, const float* __restrict__ att_d,
    float* __restrict__ h2, float* __restrict__ a2s, float* __restrict__ a2d, int N)
{
  __shared__ float Wl[128][64];    // 32 KB
  __shared__ float Xl[32][128];    // 16 KB
  __shared__ float kc[128], sc[128];
  int t = threadIdx.x;
  if (t < 128) { kc[t] = bnc1[t]; sc[t] = bnc1[128 + t]; }
  __syncthreads();
  const float4* W4 = (const float4*)W2;
  float4* Wl4 = (float4*)&Wl[0][0];
#pragma unroll
  for (int i = 0; i < 8; ++i) Wl4[t + i * 256] = W4[t + i * 256];
  int row0 = blockIdx.x * 32;
  float4* Xl4 = (float4*)&Xl[0][0];
#pragma unroll
  for (int i = 0; i < 4; ++i) {
    int id = t + i * 256;
    int r = id >> 5, c4 = id & 31;
    int gr = row0 + r;
    float4 v = (gr < N) ? *(const float4*)&v1[(size_t)gr * 128 + c4 * 4]
                        : make_float4(0.f, 0.f, 0.f, 0.f);
    int f0 = c4 * 4;
    float4 o;
    o.x = fmaxf(v.x * kc[f0]     + sc[f0],     0.f);
    o.y = fmaxf(v.y * kc[f0 + 1] + sc[f0 + 1], 0.f);
    o.z = fmaxf(v.z * kc[f0 + 2] + sc[f0 + 2], 0.f);
    o.w = fmaxf(v.w * kc[f0 + 3] + sc[f0 + 3], 0.f);
    Xl4[id] = o;
  }
  __syncthreads();
  int cg = t & 15, rg = t >> 4;  // cols cg*4 (64 cols), rows rg*2 (32 rows)
  float acc[2][4] = {};
  for (int k = 0; k < 128; k += 4) {
    float4 xv0 = *(const float4*)&Xl[rg * 2][k];
    float4 xv1 = *(const float4*)&Xl[rg * 2 + 1][k];
#pragma unroll
    for (int kk = 0; kk < 4; ++kk) {
      float4 wv = *(const float4*)&Wl[k + kk][cg * 4];
      float x0 = (&xv0.x)[kk];
      float x1 = (&xv1.x)[kk];
      acc[0][0] = fmaf(x0, wv.x, acc[0][0]);
      acc[0][1] = fmaf(x0, wv.y, acc[0][1]);
      acc[0][2] = fmaf(x0, wv.z, acc[0][2]);
      acc[0][3] = fmaf(x0, wv.w, acc[0][3]);
      acc[1][0] = fmaf(x1, wv.x, acc[1][0]);
      acc[1][1] = fmaf(x1, wv.y, acc[1][1]);
      acc[1][2] = fmaf(x1, wv.z, acc[1][2]);
      acc[1][3] = fmaf(x1, wv.w, acc[1][3]);
    }
  }
  int col = cg * 4;
  float4 asv = *(const float4*)&att_s[col];
  float4 adv = *(const float4*)&att_d[col];
#pragma unroll
  for (int r = 0; r < 2; ++r) {
    int gr = row0 + rg * 2 + r;
    if (gr < N) {
      *(float4*)&h2[(size_t)gr * 64 + col] =
          make_float4(acc[r][0], acc[r][1], acc[r][2], acc[r][3]);
      float ps = acc[r][0] * asv.x + acc[r][1] * asv.y + acc[r][2] * asv.z + acc[r][3] * asv.w;
      float pd = acc[r][0] * adv.x + acc[r][1] * adv.y + acc[r][2] * adv.z + acc[r][3] * adv.w;
      atomicAdd(&a2s[gr], ps);
      atomicAdd(&a2d[gr], pd);
    }
  }
}

// ---------------- Edge pass layer 2: one wave per edge, 1 head x 64 feats ----------------
__global__ __launch_bounds__(256) void k_edge2(
    const int* __restrict__ ei, const float* __restrict__ h2,
    const float* __restrict__ a2s, const float* __restrict__ a2d,
    float* __restrict__ s2, float* __restrict__ num2, int E, int Etot)
{
  int wid = (int)((blockIdx.x * 256 + threadIdx.x) >> 6);
  int lane = threadIdx.x & 63;
  if (wid >= Etot) return;
  int s, d;
  if (wid < E) { s = ei[wid]; d = ei[E + wid]; }
  else { s = d = wid - E; }
  float al = a2s[s] + a2d[d];
  al = (al > 0.f) ? al : LEAKY * al;
  float e = __expf(al);
  if (lane == 0) atomicAdd(&s2[d], e);
  float v = h2[(size_t)s * 64 + lane];
  atomicAdd(&num2[(size_t)d * 64 + lane], e * v);
}

// ---------------- Finalize layer 2 ----------------
__global__ __launch_bounds__(256) void k_fin2(
    float* __restrict__ num2, const float* __restrict__ s2,
    const float* __restrict__ b2, float* __restrict__ stats, int N)
{
  int t = threadIdx.x;
  int f = t & 63;
  int rg = t >> 6;    // 0..3
  int row0 = blockIdx.x * 128;
  float bias = b2[f];
  float sum = 0.f, sq = 0.f;
  for (int r = rg; r < 128; r += 4) {
    int gr = row0 + r;
    if (gr >= N) break;
    float v = num2[(size_t)gr * 64 + f] / (s2[gr] + 1e-16f) + bias;
    num2[(size_t)gr * 64 + f] = v;
    sum += v; sq += v * v;
  }
  __shared__ float ls[256], lq[256];
  ls[t] = sum; lq[t] = sq;
  __syncthreads();
  if (t < 64) {
    sum = ls[t] + ls[t + 64] + ls[t + 128] + ls[t + 192];
    sq  = lq[t] + lq[t + 64] + lq[t + 128] + lq[t + 192];
    atomicAdd(&stats[f], sum);
    atomicAdd(&stats[64 + f], sq);
  }
}

// ---------------- Final: out = relu(bn(v2)) @ linW + linb, one wave per node ----------------
__global__ __launch_bounds__(256) void k_out(
    const float* __restrict__ v2, const float* __restrict__ bnc2,
    const float* __restrict__ linW, const float* __restrict__ linb,
    float* __restrict__ out, int N)
{
  int lane = threadIdx.x & 63;
  int n = blockIdx.x * 4 + (threadIdx.x >> 6);
  if (n >= N) return;
  float v = v2[(size_t)n * 64 + lane];
  float hn = fmaxf(v * bnc2[lane] + bnc2[64 + lane], 0.f);
  float p = hn * linW[lane];
#pragma unroll
  for (int off = 32; off; off >>= 1) p += __shfl_xor(p, off);
  if (lane == 0) out[n] = p + linb[0];
}

extern "C" void kernel_launch(void* const* d_in, const int* in_sizes, int n_in,
                              void* d_out, int out_size, void* d_ws, size_t ws_size,
                              hipStream_t stream)
{
  const float* x    = (const float*)d_in[0];
  const int*   ei   = (const int*)d_in[1];
  const float* W1   = (const float*)d_in[2];
  const float* as1  = (const float*)d_in[3];
  const float* ad1  = (const float*)d_in[4];
  const float* b1   = (const float*)d_in[5];
  const float* g1   = (const float*)d_in[6];
  const float* be1  = (const float*)d_in[7];
  const float* W2   = (const float*)d_in[8];
  const float* as2  = (const float*)d_in[9];
  const float* ad2  = (const float*)d_in[10];
  const float* b2   = (const float*)d_in[11];
  const float* g2   = (const float*)d_in[12];
  const float* be2  = (const float*)d_in[13];
  const float* linW = (const float*)d_in[14];
  const float* linb = (const float*)d_in[15];
  float* out = (float*)d_out;

  int N = in_sizes[0] / 128;
  int E = in_sizes[1] / 2;
  int Etot = E + N;

  float* ws = (float*)d_ws;
  size_t o = 0;
  float* H1   = ws + o; o += (size_t)N * 128;
  float* NUM1 = ws + o; o += (size_t)N * 128;
  float* S1   = ws + o; o += (size_t)N * 2;
  float* A1S  = ws + o; o += (size_t)N * 2;
  float* A1D  = ws + o; o += (size_t)N * 2;
  float* S2v  = ws + o; o += N;
  float* A2S  = ws + o; o += N;
  float* A2D  = ws + o; o += N;
  float* ST1  = ws + o; o += 256;
  float* ST2  = ws + o; o += 128;
  float* BNC1 = ws + o; o += 256;
  float* BNC2 = ws + o; o += 128;
  // layer-2 buffers alias the (dead after edge1) h1 region
  float* H2   = H1;
  float* NUM2 = H1 + (size_t)N * 64;

  // zero: S1..ST2 contiguous (9N + 384 floats), and NUM1
  hipMemsetAsync(S1, 0, (size_t)(9 * (size_t)N + 384) * 4, stream);
  hipMemsetAsync(NUM1, 0, (size_t)N * 128 * 4, stream);

  int gb = (N + 31) / 32;
  int eb = (Etot + 3) / 4;
  int fb = (N + 127) / 128;

  k_gemm1<<<gb, 256, 0, stream>>>(x, W1, as1, ad1, H1, A1S, A1D, N);
  k_edge1<<<eb, 256, 0, stream>>>(ei, H1, A1S, A1D, S1, NUM1, E, Etot);
  k_fin1<<<fb, 256, 0, stream>>>(NUM1, S1, b1, ST1, N);
  k_bnp<<<1, 128, 0, stream>>>(ST1, g1, be1, BNC1, N, 128);
  hipMemsetAsync(NUM2, 0, (size_t)N * 64 * 4, stream);
  k_gemm2<<<gb, 256, 0, stream>>>(NUM1, W2, BNC1, as2, ad2, H2, A2S, A2D, N);
  k_edge2<<<eb, 256, 0, stream>>>(ei, H2, A2S, A2D, S2v, NUM2, E, Etot);
  k_fin2<<<fb, 256, 0, stream>>>(NUM2, S2v, b2, ST2, N);
  k_bnp<<<1, 128, 0, stream>>>(ST2, g2, be2, BNC2, N, 64);
  k_out<<<(N + 3) / 4, 256, 0, stream>>>(NUM2, BNC2, linW, linb, out, N);
}

// Round 2
// 667.592 us; speedup vs baseline: 1.4605x; 1.4605x over previous
//
#include <hip/hip_runtime.h>
#include <math.h>

#define LEAKY 0.2f

// ================= CSR build =================
__global__ __launch_bounds__(256) void k_hist(const int* __restrict__ ei,
                                              int* __restrict__ deg, int E, int Etot)
{
  int tid = blockIdx.x * 256 + threadIdx.x;
  if (tid >= Etot) return;
  int d = (tid < E) ? ei[E + tid] : tid - E;
  atomicAdd(&deg[d], 1);
}

// block covers 1024 entries (256 threads x 4); writes rowptr w/o block offset, block sum -> part
__global__ __launch_bounds__(256) void k_scan_blk(const int* __restrict__ deg,
                                                  int* __restrict__ rowptr,
                                                  int* __restrict__ part, int N)
{
  __shared__ int ls[256];
  int t = threadIdx.x;
  int base = blockIdx.x * 1024 + t * 4;
  int d0 = (base     < N) ? deg[base]     : 0;
  int d1 = (base + 1 < N) ? deg[base + 1] : 0;
  int d2 = (base + 2 < N) ? deg[base + 2] : 0;
  int d3 = (base + 3 < N) ? deg[base + 3] : 0;
  int s = d0 + d1 + d2 + d3;
  ls[t] = s;
  __syncthreads();
  for (int off = 1; off < 256; off <<= 1) {
    int v = (t >= off) ? ls[t - off] : 0;
    __syncthreads();
    ls[t] += v;
    __syncthreads();
  }
  int excl = ls[t] - s;
  if (t == 255) part[blockIdx.x] = ls[255];
  if (base     <= N) rowptr[base]     = excl;
  if (base + 1 <= N) rowptr[base + 1] = excl + d0;
  if (base + 2 <= N) rowptr[base + 2] = excl + d0 + d1;
  if (base + 3 <= N) rowptr[base + 3] = excl + d0 + d1 + d2;
}

__global__ void k_scan_part(int* __restrict__ part, int nb)
{
  int lane = threadIdx.x;  // 64 threads, nb <= 64
  int v = (lane < nb) ? part[lane] : 0;
  int inc = v;
#pragma unroll
  for (int off = 1; off < 64; off <<= 1) {
    int u = __shfl_up(inc, off);
    if (lane >= off) inc += u;
  }
  if (lane < nb) part[lane] = inc - v;
}

__global__ __launch_bounds__(256) void k_add_off(int* __restrict__ rowptr,
                                                 const int* __restrict__ part, int N)
{
  int t = threadIdx.x;
  int base = blockIdx.x * 1024 + t * 4;
  int p = part[blockIdx.x];
#pragma unroll
  for (int k = 0; k < 4; ++k)
    if (base + k <= N) rowptr[base + k] += p;
}

__global__ __launch_bounds__(256) void k_scatter(const int* __restrict__ ei,
                                                 int* __restrict__ cur,
                                                 int* __restrict__ colx, int E, int Etot)
{
  int tid = blockIdx.x * 256 + threadIdx.x;
  if (tid >= Etot) return;
  int s, d;
  if (tid < E) { s = ei[tid]; d = ei[E + tid]; }
  else { s = d = tid - E; }
  int pos = atomicAdd(&cur[d], 1);
  colx[pos] = s;
}

// ================= GEMM1: h1 = x @ W1 (N x 128 @ 128 x 128), fused att dots =================
__global__ __launch_bounds__(256) void k_gemm1(
    const float* __restrict__ x, const float* __restrict__ W,
    const float* __restrict__ att_s, const float* __restrict__ att_d,
    float* __restrict__ h1, float* __restrict__ a1s, float* __restrict__ a1d, int N)
{
  __shared__ float Wl[128][128];
  __shared__ float Xl[32][128];
  int t = threadIdx.x;
  const float4* W4 = (const float4*)W;
  float4* Wl4 = (float4*)&Wl[0][0];
#pragma unroll
  for (int i = 0; i < 16; ++i) Wl4[t + i * 256] = W4[t + i * 256];
  int row0 = blockIdx.x * 32;
  const float4* X4 = (const float4*)x;
  float4* Xl4 = (float4*)&Xl[0][0];
#pragma unroll
  for (int i = 0; i < 4; ++i) {
    int id = t + i * 256;
    int r = id >> 5, c = id & 31;
    int gr = row0 + r;
    Xl4[id] = (gr < N) ? X4[(size_t)gr * 32 + c] : make_float4(0.f, 0.f, 0.f, 0.f);
  }
  __syncthreads();
  int cg = t & 31, rg = t >> 5;
  float acc[4][4] = {};
  for (int k = 0; k < 128; k += 4) {
    float4 xv[4];
#pragma unroll
    for (int r = 0; r < 4; ++r) xv[r] = *(const float4*)&Xl[rg * 4 + r][k];
#pragma unroll
    for (int kk = 0; kk < 4; ++kk) {
      float4 wv = *(const float4*)&Wl[k + kk][cg * 4];
#pragma unroll
      for (int r = 0; r < 4; ++r) {
        float xs = (&xv[r].x)[kk];
        acc[r][0] = fmaf(xs, wv.x, acc[r][0]);
        acc[r][1] = fmaf(xs, wv.y, acc[r][1]);
        acc[r][2] = fmaf(xs, wv.z, acc[r][2]);
        acc[r][3] = fmaf(xs, wv.w, acc[r][3]);
      }
    }
  }
  int col = cg * 4;
  int h = col >> 6;
  float4 asv = *(const float4*)&att_s[col];
  float4 adv = *(const float4*)&att_d[col];
#pragma unroll
  for (int r = 0; r < 4; ++r) {
    int gr = row0 + rg * 4 + r;
    if (gr < N) {
      *(float4*)&h1[(size_t)gr * 128 + col] =
          make_float4(acc[r][0], acc[r][1], acc[r][2], acc[r][3]);
      float ps = acc[r][0] * asv.x + acc[r][1] * asv.y + acc[r][2] * asv.z + acc[r][3] * asv.w;
      float pd = acc[r][0] * adv.x + acc[r][1] * adv.y + acc[r][2] * adv.z + acc[r][3] * adv.w;
      atomicAdd(&a1s[gr * 2 + h], ps);
      atomicAdd(&a1d[gr * 2 + h], pd);
    }
  }
}

// ================= Aggregate layer 1: wave per (node,head), gather over CSR =================
// Fuses: softmax denom, numerator, divide, +bias, BN-stat accumulation.
__global__ __launch_bounds__(256) void k_agg1(
    const int* __restrict__ rowptr, const int* __restrict__ colx,
    const float* __restrict__ h1, const float* __restrict__ a1s,
    const float* __restrict__ a1d, const float* __restrict__ b1,
    float* __restrict__ v1, float* __restrict__ stats, int N, int G)
{
  int t = threadIdx.x;
  int lane = t & 63;
  int w = t >> 6;      // wave 0..3
  int h = w & 1;       // head
  int p = w >> 1;      // node slot 0..1
  int f = (h << 6) + lane;
  float bias = b1[f];
  float bns = 0.f, bnq = 0.f;
  for (int n = blockIdx.x * 2 + p; n < N; n += G * 2) {
    float ad = a1d[n * 2 + h];
    int start = rowptr[n], end = rowptr[n + 1];
    float se = 0.f, acc = 0.f;
    for (int base = start; base < end; base += 64) {
      int cnt = end - base; if (cnt > 64) cnt = 64;
      int sl = 0; float ev = 0.f;
      if (lane < cnt) {
        sl = colx[base + lane];
        float av = a1s[sl * 2 + h] + ad;
        av = (av > 0.f) ? av : LEAKY * av;
        ev = __expf(av);
      }
      for (int j = 0; j < cnt; ++j) {
        int s = __shfl(sl, j);
        float e = __shfl(ev, j);
        se += e;
        acc = fmaf(e, h1[(size_t)s * 128 + f], acc);
      }
    }
    float outv = acc / se + bias;
    v1[(size_t)n * 128 + f] = outv;
    bns += outv; bnq += outv * outv;
  }
  __shared__ float lss[2][128], lsq[2][128];
  lss[p][f] = bns; lsq[p][f] = bnq;
  __syncthreads();
  if (t < 128) {
    atomicAdd(&stats[t],       lss[0][t] + lss[1][t]);
    atomicAdd(&stats[128 + t], lsq[0][t] + lsq[1][t]);
  }
}

// ================= BN params =================
__global__ void k_bnp(const float* __restrict__ stats, const float* __restrict__ g,
                      const float* __restrict__ be, float* __restrict__ bnc, int N, int F)
{
  int f = threadIdx.x;
  if (f < F) {
    float mu = stats[f] / (float)N;
    float var = stats[F + f] / (float)N - mu * mu;
    float k = g[f] * rsqrtf(var + 1e-5f);
    bnc[f] = k;
    bnc[F + f] = be[f] - mu * k;
  }
}

// ================= GEMM2: h2 = relu(bn(v1)) @ W2 (N x 128 @ 128 x 64), fused att dots ======
__global__ __launch_bounds__(256) void k_gemm2(
    const float* __restrict__ v1, const float* __restrict__ W2,
    const float* __restrict__ bnc1,
    const float* __restrict__ att_s, const float* __restrict__ att_d,
    float* __restrict__ h2, float* __restrict__ a2s, float* __restrict__ a2d, int N)
{
  __shared__ float Wl[128][64];
  __shared__ float Xl[32][128];
  __shared__ float kc[128], sc[128];
  int t = threadIdx.x;
  if (t < 128) { kc[t] = bnc1[t]; sc[t] = bnc1[128 + t]; }
  __syncthreads();
  const float4* W4 = (const float4*)W2;
  float4* Wl4 = (float4*)&Wl[0][0];
#pragma unroll
  for (int i = 0; i < 8; ++i) Wl4[t + i * 256] = W4[t + i * 256];
  int row0 = blockIdx.x * 32;
  float4* Xl4 = (float4*)&Xl[0][0];
#pragma unroll
  for (int i = 0; i < 4; ++i) {
    int id = t + i * 256;
    int r = id >> 5, c4 = id & 31;
    int gr = row0 + r;
    float4 v = (gr < N) ? *(const float4*)&v1[(size_t)gr * 128 + c4 * 4]
                        : make_float4(0.f, 0.f, 0.f, 0.f);
    int f0 = c4 * 4;
    float4 o;
    o.x = fmaxf(v.x * kc[f0]     + sc[f0],     0.f);
    o.y = fmaxf(v.y * kc[f0 + 1] + sc[f0 + 1], 0.f);
    o.z = fmaxf(v.z * kc[f0 + 2] + sc[f0 + 2], 0.f);
    o.w = fmaxf(v.w * kc[f0 + 3] + sc[f0 + 3], 0.f);
    Xl4[id] = o;
  }
  __syncthreads();
  int cg = t & 15, rg = t >> 4;
  float acc[2][4] = {};
  for (int k = 0; k < 128; k += 4) {
    float4 xv0 = *(const float4*)&Xl[rg * 2][k];
    float4 xv1 = *(const float4*)&Xl[rg * 2 + 1][k];
#pragma unroll
    for (int kk = 0; kk < 4; ++kk) {
      float4 wv = *(const float4*)&Wl[k + kk][cg * 4];
      float x0 = (&xv0.x)[kk];
      float x1 = (&xv1.x)[kk];
      acc[0][0] = fmaf(x0, wv.x, acc[0][0]);
      acc[0][1] = fmaf(x0, wv.y, acc[0][1]);
      acc[0][2] = fmaf(x0, wv.z, acc[0][2]);
      acc[0][3] = fmaf(x0, wv.w, acc[0][3]);
      acc[1][0] = fmaf(x1, wv.x, acc[1][0]);
      acc[1][1] = fmaf(x1, wv.y, acc[1][1]);
      acc[1][2] = fmaf(x1, wv.z, acc[1][2]);
      acc[1][3] = fmaf(x1, wv.w, acc[1][3]);
    }
  }
  int col = cg * 4;
  float4 asv = *(const float4*)&att_s[col];
  float4 adv = *(const float4*)&att_d[col];
#pragma unroll
  for (int r = 0; r < 2; ++r) {
    int gr = row0 + rg * 2 + r;
    if (gr < N) {
      *(float4*)&h2[(size_t)gr * 64 + col] =
          make_float4(acc[r][0], acc[r][1], acc[r][2], acc[r][3]);
      float ps = acc[r][0] * asv.x + acc[r][1] * asv.y + acc[r][2] * asv.z + acc[r][3] * asv.w;
      float pd = acc[r][0] * adv.x + acc[r][1] * adv.y + acc[r][2] * adv.z + acc[r][3] * adv.w;
      atomicAdd(&a2s[gr], ps);
      atomicAdd(&a2d[gr], pd);
    }
  }
}

// ================= Aggregate layer 2: wave per node =================
__global__ __launch_bounds__(256) void k_agg2(
    const int* __restrict__ rowptr, const int* __restrict__ colx,
    const float* __restrict__ h2, const float* __restrict__ a2s,
    const float* __restrict__ a2d, const float* __restrict__ b2,
    float* __restrict__ v2, float* __restrict__ stats, int N, int G)
{
  int t = threadIdx.x;
  int lane = t & 63;
  int w = t >> 6;
  float bias = b2[lane];
  float bns = 0.f, bnq = 0.f;
  for (int n = blockIdx.x * 4 + w; n < N; n += G * 4) {
    float ad = a2d[n];
    int start = rowptr[n], end = rowptr[n + 1];
    float se = 0.f, acc = 0.f;
    for (int base = start; base < end; base += 64) {
      int cnt = end - base; if (cnt > 64) cnt = 64;
      int sl = 0; float ev = 0.f;
      if (lane < cnt) {
        sl = colx[base + lane];
        float av = a2s[sl] + ad;
        av = (av > 0.f) ? av : LEAKY * av;
        ev = __expf(av);
      }
      for (int j = 0; j < cnt; ++j) {
        int s = __shfl(sl, j);
        float e = __shfl(ev, j);
        se += e;
        acc = fmaf(e, h2[(size_t)s * 64 + lane], acc);
      }
    }
    float outv = acc / se + bias;
    v2[(size_t)n * 64 + lane] = outv;
    bns += outv; bnq += outv * outv;
  }
  __shared__ float lss[4][64], lsq[4][64];
  lss[w][lane] = bns; lsq[w][lane] = bnq;
  __syncthreads();
  if (t < 64) {
    atomicAdd(&stats[t],      lss[0][t] + lss[1][t] + lss[2][t] + lss[3][t]);
    atomicAdd(&stats[64 + t], lsq[0][t] + lsq[1][t] + lsq[2][t] + lsq[3][t]);
  }
}

// ================= Final: out = relu(bn(v2)) @ linW + linb =================
__global__ __launch_bounds__(256) void k_out(
    const float* __restrict__ v2, const float* __restrict__ bnc2,
    const float* __restrict__ linW, const float* __restrict__ linb,
    float* __restrict__ out, int N)
{
  int lane = threadIdx.x & 63;
  int n = blockIdx.x * 4 + (threadIdx.x >> 6);
  if (n >= N) return;
  float v = v2[(size_t)n * 64 + lane];
  float hn = fmaxf(v * bnc2[lane] + bnc2[64 + lane], 0.f);
  float p = hn * linW[lane];
#pragma unroll
  for (int off = 32; off; off >>= 1) p += __shfl_xor(p, off);
  if (lane == 0) out[n] = p + linb[0];
}

extern "C" void kernel_launch(void* const* d_in, const int* in_sizes, int n_in,
                              void* d_out, int out_size, void* d_ws, size_t ws_size,
                              hipStream_t stream)
{
  const float* x    = (const float*)d_in[0];
  const int*   ei   = (const int*)d_in[1];
  const float* W1   = (const float*)d_in[2];
  const float* as1  = (const float*)d_in[3];
  const float* ad1  = (const float*)d_in[4];
  const float* b1   = (const float*)d_in[5];
  const float* g1   = (const float*)d_in[6];
  const float* be1  = (const float*)d_in[7];
  const float* W2   = (const float*)d_in[8];
  const float* as2  = (const float*)d_in[9];
  const float* ad2  = (const float*)d_in[10];
  const float* b2   = (const float*)d_in[11];
  const float* g2   = (const float*)d_in[12];
  const float* be2  = (const float*)d_in[13];
  const float* linW = (const float*)d_in[14];
  const float* linb = (const float*)d_in[15];
  float* out = (float*)d_out;

  int N = in_sizes[0] / 128;
  int E = in_sizes[1] / 2;
  int Etot = E + N;

  float* ws = (float*)d_ws;
  size_t o = 0;
  float* H1   = ws + o; o += (size_t)N * 128;
  float* V1   = ws + o; o += (size_t)N * 128;
  float* A1S  = ws + o; o += (size_t)N * 2;   // zero-region start
  float* A1D  = ws + o; o += (size_t)N * 2;
  float* A2S  = ws + o; o += N;
  float* A2D  = ws + o; o += N;
  float* ST1  = ws + o; o += 256;
  float* ST2  = ws + o; o += 128;             // zero-region end (6N + 384)
  float* BNC1 = ws + o; o += 256;
  float* BNC2 = ws + o; o += 128;
  int* ROWPTR = (int*)(ws + o); o += (size_t)N + 1;
  int* COL    = (int*)(ws + o); o += (size_t)Etot;
  int* DEG    = (int*)(ws + o); o += N;       // reused as scatter cursor
  int* PART   = (int*)(ws + o); o += 64;
  // layer-2 buffers alias the (dead after agg1) H1 region
  float* H2 = H1;
  float* V2 = H1 + (size_t)N * 64;

  hipMemsetAsync(A1S, 0, (size_t)(6 * (size_t)N + 384) * 4, stream);
  hipMemsetAsync(DEG, 0, (size_t)N * 4, stream);

  int ebk = (Etot + 255) / 256;
  int nb = (N + 1024) / 1024;   // ceil((N+1)/1024)
  int gb = (N + 31) / 32;
  const int G = 1024;

  k_hist<<<ebk, 256, 0, stream>>>(ei, DEG, E, Etot);
  k_scan_blk<<<nb, 256, 0, stream>>>(DEG, ROWPTR, PART, N);
  k_scan_part<<<1, 64, 0, stream>>>(PART, nb);
  k_add_off<<<nb, 256, 0, stream>>>(ROWPTR, PART, N);
  hipMemcpyAsync(DEG, ROWPTR, (size_t)N * 4, hipMemcpyDeviceToDevice, stream);
  k_scatter<<<ebk, 256, 0, stream>>>(ei, DEG, COL, E, Etot);

  k_gemm1<<<gb, 256, 0, stream>>>(x, W1, as1, ad1, H1, A1S, A1D, N);
  k_agg1<<<G, 256, 0, stream>>>(ROWPTR, COL, H1, A1S, A1D, b1, V1, ST1, N, G);
  k_bnp<<<1, 128, 0, stream>>>(ST1, g1, be1, BNC1, N, 128);
  k_gemm2<<<gb, 256, 0, stream>>>(V1, W2, BNC1, as2, ad2, H2, A2S, A2D, N);
  k_agg2<<<G, 256, 0, stream>>>(ROWPTR, COL, H2, A2S, A2D, b2, V2, ST2, N, G);
  k_bnp<<<1, 128, 0, stream>>>(ST2, g2, be2, BNC2, N, 64);
  k_out<<<(N + 3) / 4, 256, 0, stream>>>(V2, BNC2, linW, linb, out, N);
}

// Round 3
// 355.348 us; speedup vs baseline: 2.7438x; 1.8787x over previous
//
#include <hip/hip_runtime.h>
#include <math.h>

#define LEAKY 0.2f

// ================= CSR build =================
__global__ __launch_bounds__(256) void k_hist(const int* __restrict__ ei,
                                              int* __restrict__ deg, int E, int Etot)
{
  int tid = blockIdx.x * 256 + threadIdx.x;
  if (tid >= Etot) return;
  int d = (tid < E) ? ei[E + tid] : tid - E;
  atomicAdd(&deg[d], 1);
}

__global__ __launch_bounds__(256) void k_scan_blk(const int* __restrict__ deg,
                                                  int* __restrict__ rowptr,
                                                  int* __restrict__ part, int N)
{
  __shared__ int ls[256];
  int t = threadIdx.x;
  int base = blockIdx.x * 1024 + t * 4;
  int d0 = (base     < N) ? deg[base]     : 0;
  int d1 = (base + 1 < N) ? deg[base + 1] : 0;
  int d2 = (base + 2 < N) ? deg[base + 2] : 0;
  int d3 = (base + 3 < N) ? deg[base + 3] : 0;
  int s = d0 + d1 + d2 + d3;
  ls[t] = s;
  __syncthreads();
  for (int off = 1; off < 256; off <<= 1) {
    int v = (t >= off) ? ls[t - off] : 0;
    __syncthreads();
    ls[t] += v;
    __syncthreads();
  }
  int excl = ls[t] - s;
  if (t == 255) part[blockIdx.x] = ls[255];
  if (base     <= N) rowptr[base]     = excl;
  if (base + 1 <= N) rowptr[base + 1] = excl + d0;
  if (base + 2 <= N) rowptr[base + 2] = excl + d0 + d1;
  if (base + 3 <= N) rowptr[base + 3] = excl + d0 + d1 + d2;
}

__global__ void k_scan_part(int* __restrict__ part, int nb)
{
  int lane = threadIdx.x;
  int v = (lane < nb) ? part[lane] : 0;
  int inc = v;
#pragma unroll
  for (int off = 1; off < 64; off <<= 1) {
    int u = __shfl_up(inc, off);
    if (lane >= off) inc += u;
  }
  if (lane < nb) part[lane] = inc - v;
}

__global__ __launch_bounds__(256) void k_add_off(int* __restrict__ rowptr,
                                                 const int* __restrict__ part, int N)
{
  int t = threadIdx.x;
  int base = blockIdx.x * 1024 + t * 4;
  int p = part[blockIdx.x];
#pragma unroll
  for (int k = 0; k < 4; ++k)
    if (base + k <= N) rowptr[base + k] += p;
}

__global__ __launch_bounds__(256) void k_scatter(const int* __restrict__ ei,
                                                 int* __restrict__ cur,
                                                 int* __restrict__ colx, int E, int Etot)
{
  int tid = blockIdx.x * 256 + threadIdx.x;
  if (tid >= Etot) return;
  int s, d;
  if (tid < E) { s = ei[tid]; d = ei[E + tid]; }
  else { s = d = tid - E; }
  int pos = atomicAdd(&cur[d], 1);
  colx[pos] = s;
}

// ================= GEMM1: h1 = x @ W1 (N x 128 @ 128 x 128), fused att dots =================
__global__ __launch_bounds__(256) void k_gemm1(
    const float* __restrict__ x, const float* __restrict__ W,
    const float* __restrict__ att_s, const float* __restrict__ att_d,
    float* __restrict__ h1, float* __restrict__ a1s, float* __restrict__ a1d, int N)
{
  __shared__ float Wl[128][128];
  __shared__ float Xl[32][128];
  int t = threadIdx.x;
  const float4* W4 = (const float4*)W;
  float4* Wl4 = (float4*)&Wl[0][0];
#pragma unroll
  for (int i = 0; i < 16; ++i) Wl4[t + i * 256] = W4[t + i * 256];
  int row0 = blockIdx.x * 32;
  const float4* X4 = (const float4*)x;
  float4* Xl4 = (float4*)&Xl[0][0];
#pragma unroll
  for (int i = 0; i < 4; ++i) {
    int id = t + i * 256;
    int r = id >> 5, c = id & 31;
    int gr = row0 + r;
    Xl4[id] = (gr < N) ? X4[(size_t)gr * 32 + c] : make_float4(0.f, 0.f, 0.f, 0.f);
  }
  __syncthreads();
  int cg = t & 31, rg = t >> 5;
  float acc[4][4] = {};
  for (int k = 0; k < 128; k += 4) {
    float4 xv[4];
#pragma unroll
    for (int r = 0; r < 4; ++r) xv[r] = *(const float4*)&Xl[rg * 4 + r][k];
#pragma unroll
    for (int kk = 0; kk < 4; ++kk) {
      float4 wv = *(const float4*)&Wl[k + kk][cg * 4];
#pragma unroll
      for (int r = 0; r < 4; ++r) {
        float xs = (&xv[r].x)[kk];
        acc[r][0] = fmaf(xs, wv.x, acc[r][0]);
        acc[r][1] = fmaf(xs, wv.y, acc[r][1]);
        acc[r][2] = fmaf(xs, wv.z, acc[r][2]);
        acc[r][3] = fmaf(xs, wv.w, acc[r][3]);
      }
    }
  }
  int col = cg * 4;
  int h = (t >> 4) & 1;
  float4 asv = *(const float4*)&att_s[col];
  float4 adv = *(const float4*)&att_d[col];
#pragma unroll
  for (int r = 0; r < 4; ++r) {
    int gr = row0 + rg * 4 + r;
    float ps = acc[r][0] * asv.x + acc[r][1] * asv.y + acc[r][2] * asv.z + acc[r][3] * asv.w;
    float pd = acc[r][0] * adv.x + acc[r][1] * adv.y + acc[r][2] * adv.z + acc[r][3] * adv.w;
    // reduce across the 16 col-groups of this (row, head): lanes with same t>>4
    ps += __shfl_xor(ps, 1); ps += __shfl_xor(ps, 2); ps += __shfl_xor(ps, 4); ps += __shfl_xor(ps, 8);
    pd += __shfl_xor(pd, 1); pd += __shfl_xor(pd, 2); pd += __shfl_xor(pd, 4); pd += __shfl_xor(pd, 8);
    if (gr < N) {
      *(float4*)&h1[(size_t)gr * 128 + col] =
          make_float4(acc[r][0], acc[r][1], acc[r][2], acc[r][3]);
      if ((t & 15) == 0) { a1s[gr * 2 + h] = ps; a1d[gr * 2 + h] = pd; }
    }
  }
}

// ================= Aggregate layer 1: wave per node, float2 feats, 4x unrolled gather ======
__global__ __launch_bounds__(256) void k_agg1(
    const int* __restrict__ rowptr, const int* __restrict__ colx,
    const float* __restrict__ h1, const float* __restrict__ a1s,
    const float* __restrict__ a1d, const float* __restrict__ b1,
    float* __restrict__ v1, float* __restrict__ stats, int N, int NW)
{
  int t = threadIdx.x;
  int lane = t & 63;
  int w = t >> 6;
  int gw = blockIdx.x * 4 + w;
  bool hi = lane >= 32;                 // head of this lane's features {2l, 2l+1}
  float2 bias = *(const float2*)&b1[lane * 2];
  float bns0 = 0.f, bns1 = 0.f, bnq0 = 0.f, bnq1 = 0.f;
  for (int n = gw; n < N; n += NW) {
    float2 ad = *(const float2*)&a1d[n * 2];
    int start = rowptr[n], end = rowptr[n + 1];
    float se = 0.f;
    float2 acc = make_float2(0.f, 0.f);
    for (int base = start; base < end; base += 64) {
      int cnt = end - base; if (cnt > 64) cnt = 64;
      int sl = 0; float e0 = 0.f, e1 = 0.f;
      if (lane < cnt) {
        sl = colx[base + lane];
        float2 av = *(const float2*)&a1s[sl * 2];
        float x0 = av.x + ad.x, x1 = av.y + ad.y;
        x0 = (x0 > 0.f) ? x0 : LEAKY * x0;
        x1 = (x1 > 0.f) ? x1 : LEAKY * x1;
        e0 = __expf(x0); e1 = __expf(x1);
      }
      int j = 0, lim = cnt & ~3;
      for (; j < lim; j += 4) {
        int s0 = __shfl(sl, j), s1 = __shfl(sl, j + 1), s2 = __shfl(sl, j + 2), s3 = __shfl(sl, j + 3);
        float p0 = __shfl(e0, j),     q0 = __shfl(e1, j);
        float p1 = __shfl(e0, j + 1), q1 = __shfl(e1, j + 1);
        float p2 = __shfl(e0, j + 2), q2 = __shfl(e1, j + 2);
        float p3 = __shfl(e0, j + 3), q3 = __shfl(e1, j + 3);
        float2 r0 = *(const float2*)&h1[(size_t)s0 * 128 + lane * 2];
        float2 r1 = *(const float2*)&h1[(size_t)s1 * 128 + lane * 2];
        float2 r2 = *(const float2*)&h1[(size_t)s2 * 128 + lane * 2];
        float2 r3 = *(const float2*)&h1[(size_t)s3 * 128 + lane * 2];
        float w0 = hi ? q0 : p0, w1 = hi ? q1 : p1, w2 = hi ? q2 : p2, w3 = hi ? q3 : p3;
        se += (w0 + w1) + (w2 + w3);
        acc.x = fmaf(w0, r0.x, acc.x); acc.y = fmaf(w0, r0.y, acc.y);
        acc.x = fmaf(w1, r1.x, acc.x); acc.y = fmaf(w1, r1.y, acc.y);
        acc.x = fmaf(w2, r2.x, acc.x); acc.y = fmaf(w2, r2.y, acc.y);
        acc.x = fmaf(w3, r3.x, acc.x); acc.y = fmaf(w3, r3.y, acc.y);
      }
      for (; j < cnt; ++j) {
        int s0 = __shfl(sl, j);
        float p0 = __shfl(e0, j), q0 = __shfl(e1, j);
        float2 r0 = *(const float2*)&h1[(size_t)s0 * 128 + lane * 2];
        float w0 = hi ? q0 : p0;
        se += w0;
        acc.x = fmaf(w0, r0.x, acc.x); acc.y = fmaf(w0, r0.y, acc.y);
      }
    }
    float inv = 1.f / se;
    float2 o;
    o.x = acc.x * inv + bias.x;
    o.y = acc.y * inv + bias.y;
    *(float2*)&v1[(size_t)n * 128 + lane * 2] = o;
    bns0 += o.x; bnq0 += o.x * o.x;
    bns1 += o.y; bnq1 += o.y * o.y;
  }
  __shared__ float reds[4][128], redq[4][128];
  reds[w][lane * 2] = bns0; reds[w][lane * 2 + 1] = bns1;
  redq[w][lane * 2] = bnq0; redq[w][lane * 2 + 1] = bnq1;
  __syncthreads();
  if (t < 128) {
    atomicAdd(&stats[t],       reds[0][t] + reds[1][t] + reds[2][t] + reds[3][t]);
    atomicAdd(&stats[128 + t], redq[0][t] + redq[1][t] + redq[2][t] + redq[3][t]);
  }
}

// ================= BN params =================
__global__ void k_bnp(const float* __restrict__ stats, const float* __restrict__ g,
                      const float* __restrict__ be, float* __restrict__ bnc, int N, int F)
{
  int f = threadIdx.x;
  if (f < F) {
    float mu = stats[f] / (float)N;
    float var = stats[F + f] / (float)N - mu * mu;
    float k = g[f] * rsqrtf(var + 1e-5f);
    bnc[f] = k;
    bnc[F + f] = be[f] - mu * k;
  }
}

// ================= GEMM2: h2 = relu(bn(v1)) @ W2 (N x 128 @ 128 x 64), fused att dots ======
__global__ __launch_bounds__(256) void k_gemm2(
    const float* __restrict__ v1, const float* __restrict__ W2,
    const float* __restrict__ bnc1,
    const float* __restrict__ att_s, const float* __restrict__ att_d,
    float* __restrict__ h2, float* __restrict__ a2s, float* __restrict__ a2d, int N)
{
  __shared__ float Wl[128][64];
  __shared__ float Xl[32][128];
  __shared__ float kc[128], sc[128];
  int t = threadIdx.x;
  if (t < 128) { kc[t] = bnc1[t]; sc[t] = bnc1[128 + t]; }
  __syncthreads();
  const float4* W4 = (const float4*)W2;
  float4* Wl4 = (float4*)&Wl[0][0];
#pragma unroll
  for (int i = 0; i < 8; ++i) Wl4[t + i * 256] = W4[t + i * 256];
  int row0 = blockIdx.x * 32;
  float4* Xl4 = (float4*)&Xl[0][0];
#pragma unroll
  for (int i = 0; i < 4; ++i) {
    int id = t + i * 256;
    int r = id >> 5, c4 = id & 31;
    int gr = row0 + r;
    float4 v = (gr < N) ? *(const float4*)&v1[(size_t)gr * 128 + c4 * 4]
                        : make_float4(0.f, 0.f, 0.f, 0.f);
    int f0 = c4 * 4;
    float4 o;
    o.x = fmaxf(v.x * kc[f0]     + sc[f0],     0.f);
    o.y = fmaxf(v.y * kc[f0 + 1] + sc[f0 + 1], 0.f);
    o.z = fmaxf(v.z * kc[f0 + 2] + sc[f0 + 2], 0.f);
    o.w = fmaxf(v.w * kc[f0 + 3] + sc[f0 + 3], 0.f);
    Xl4[id] = o;
  }
  __syncthreads();
  int cg = t & 15, rg = t >> 4;
  float acc[2][4] = {};
  for (int k = 0; k < 128; k += 4) {
    float4 xv0 = *(const float4*)&Xl[rg * 2][k];
    float4 xv1 = *(const float4*)&Xl[rg * 2 + 1][k];
#pragma unroll
    for (int kk = 0; kk < 4; ++kk) {
      float4 wv = *(const float4*)&Wl[k + kk][cg * 4];
      float x0 = (&xv0.x)[kk];
      float x1 = (&xv1.x)[kk];
      acc[0][0] = fmaf(x0, wv.x, acc[0][0]);
      acc[0][1] = fmaf(x0, wv.y, acc[0][1]);
      acc[0][2] = fmaf(x0, wv.z, acc[0][2]);
      acc[0][3] = fmaf(x0, wv.w, acc[0][3]);
      acc[1][0] = fmaf(x1, wv.x, acc[1][0]);
      acc[1][1] = fmaf(x1, wv.y, acc[1][1]);
      acc[1][2] = fmaf(x1, wv.z, acc[1][2]);
      acc[1][3] = fmaf(x1, wv.w, acc[1][3]);
    }
  }
  int col = cg * 4;
  float4 asv = *(const float4*)&att_s[col];
  float4 adv = *(const float4*)&att_d[col];
#pragma unroll
  for (int r = 0; r < 2; ++r) {
    int gr = row0 + rg * 2 + r;
    float ps = acc[r][0] * asv.x + acc[r][1] * asv.y + acc[r][2] * asv.z + acc[r][3] * asv.w;
    float pd = acc[r][0] * adv.x + acc[r][1] * adv.y + acc[r][2] * adv.z + acc[r][3] * adv.w;
    ps += __shfl_xor(ps, 1); ps += __shfl_xor(ps, 2); ps += __shfl_xor(ps, 4); ps += __shfl_xor(ps, 8);
    pd += __shfl_xor(pd, 1); pd += __shfl_xor(pd, 2); pd += __shfl_xor(pd, 4); pd += __shfl_xor(pd, 8);
    if (gr < N) {
      *(float4*)&h2[(size_t)gr * 64 + col] =
          make_float4(acc[r][0], acc[r][1], acc[r][2], acc[r][3]);
      if ((t & 15) == 0) { a2s[gr] = ps; a2d[gr] = pd; }
    }
  }
}

// ================= Aggregate layer 2: wave per node, 4x unrolled gather =================
__global__ __launch_bounds__(256) void k_agg2(
    const int* __restrict__ rowptr, const int* __restrict__ colx,
    const float* __restrict__ h2, const float* __restrict__ a2s,
    const float* __restrict__ a2d, const float* __restrict__ b2,
    float* __restrict__ v2, float* __restrict__ stats, int N, int NW)
{
  int t = threadIdx.x;
  int lane = t & 63;
  int w = t >> 6;
  int gw = blockIdx.x * 4 + w;
  float bias = b2[lane];
  float bns = 0.f, bnq = 0.f;
  for (int n = gw; n < N; n += NW) {
    float ad = a2d[n];
    int start = rowptr[n], end = rowptr[n + 1];
    float se = 0.f, acc = 0.f;
    for (int base = start; base < end; base += 64) {
      int cnt = end - base; if (cnt > 64) cnt = 64;
      int sl = 0; float ev = 0.f;
      if (lane < cnt) {
        sl = colx[base + lane];
        float av = a2s[sl] + ad;
        av = (av > 0.f) ? av : LEAKY * av;
        ev = __expf(av);
      }
      int j = 0, lim = cnt & ~3;
      for (; j < lim; j += 4) {
        int s0 = __shfl(sl, j), s1 = __shfl(sl, j + 1), s2 = __shfl(sl, j + 2), s3 = __shfl(sl, j + 3);
        float e0 = __shfl(ev, j), e1 = __shfl(ev, j + 1), e2 = __shfl(ev, j + 2), e3 = __shfl(ev, j + 3);
        float r0 = h2[(size_t)s0 * 64 + lane];
        float r1 = h2[(size_t)s1 * 64 + lane];
        float r2 = h2[(size_t)s2 * 64 + lane];
        float r3 = h2[(size_t)s3 * 64 + lane];
        se += (e0 + e1) + (e2 + e3);
        acc = fmaf(e0, r0, acc);
        acc = fmaf(e1, r1, acc);
        acc = fmaf(e2, r2, acc);
        acc = fmaf(e3, r3, acc);
      }
      for (; j < cnt; ++j) {
        int s0 = __shfl(sl, j);
        float e0 = __shfl(ev, j);
        float r0 = h2[(size_t)s0 * 64 + lane];
        se += e0;
        acc = fmaf(e0, r0, acc);
      }
    }
    float outv = acc / se + bias;
    v2[(size_t)n * 64 + lane] = outv;
    bns += outv; bnq += outv * outv;
  }
  __shared__ float reds[4][64], redq[4][64];
  reds[w][lane] = bns; redq[w][lane] = bnq;
  __syncthreads();
  if (t < 64) {
    atomicAdd(&stats[t],      reds[0][t] + reds[1][t] + reds[2][t] + reds[3][t]);
    atomicAdd(&stats[64 + t], redq[0][t] + redq[1][t] + redq[2][t] + redq[3][t]);
  }
}

// ================= Final: out = relu(bn(v2)) @ linW + linb =================
__global__ __launch_bounds__(256) void k_out(
    const float* __restrict__ v2, const float* __restrict__ bnc2,
    const float* __restrict__ linW, const float* __restrict__ linb,
    float* __restrict__ out, int N)
{
  int lane = threadIdx.x & 63;
  int n = blockIdx.x * 4 + (threadIdx.x >> 6);
  if (n >= N) return;
  float v = v2[(size_t)n * 64 + lane];
  float hn = fmaxf(v * bnc2[lane] + bnc2[64 + lane], 0.f);
  float p = hn * linW[lane];
#pragma unroll
  for (int off = 32; off; off >>= 1) p += __shfl_xor(p, off);
  if (lane == 0) out[n] = p + linb[0];
}

extern "C" void kernel_launch(void* const* d_in, const int* in_sizes, int n_in,
                              void* d_out, int out_size, void* d_ws, size_t ws_size,
                              hipStream_t stream)
{
  const float* x    = (const float*)d_in[0];
  const int*   ei   = (const int*)d_in[1];
  const float* W1   = (const float*)d_in[2];
  const float* as1  = (const float*)d_in[3];
  const float* ad1  = (const float*)d_in[4];
  const float* b1   = (const float*)d_in[5];
  const float* g1   = (const float*)d_in[6];
  const float* be1  = (const float*)d_in[7];
  const float* W2   = (const float*)d_in[8];
  const float* as2  = (const float*)d_in[9];
  const float* ad2  = (const float*)d_in[10];
  const float* b2   = (const float*)d_in[11];
  const float* g2   = (const float*)d_in[12];
  const float* be2  = (const float*)d_in[13];
  const float* linW = (const float*)d_in[14];
  const float* linb = (const float*)d_in[15];
  float* out = (float*)d_out;

  int N = in_sizes[0] / 128;
  int E = in_sizes[1] / 2;
  int Etot = E + N;

  float* ws = (float*)d_ws;
  size_t o = 0;
  float* H1   = ws + o; o += (size_t)N * 128;
  float* V1   = ws + o; o += (size_t)N * 128;
  float* A1S  = ws + o; o += (size_t)N * 2;
  float* A1D  = ws + o; o += (size_t)N * 2;
  float* A2S  = ws + o; o += N;
  float* A2D  = ws + o; o += N;
  float* ST1  = ws + o; o += 256;              // zero-region start
  float* ST2  = ws + o; o += 128;              // zero-region end (384 floats)
  float* BNC1 = ws + o; o += 256;
  float* BNC2 = ws + o; o += 128;
  int* ROWPTR = (int*)(ws + o); o += (size_t)N + 1;
  int* COL    = (int*)(ws + o); o += (size_t)Etot;
  int* DEG    = (int*)(ws + o); o += N;        // reused as scatter cursor
  int* PART   = (int*)(ws + o); o += 64;
  float* H2 = H1;                              // layer-2 aliases dead H1 region
  float* V2 = H1 + (size_t)N * 64;

  hipMemsetAsync(ST1, 0, 384 * 4, stream);
  hipMemsetAsync(DEG, 0, (size_t)N * 4, stream);

  int ebk = (Etot + 255) / 256;
  int nb = (N + 1024) / 1024;
  int gb = (N + 31) / 32;
  const int AB = 2048;               // agg blocks -> 8192 waves (full residency)
  const int NW = AB * 4;

  k_hist<<<ebk, 256, 0, stream>>>(ei, DEG, E, Etot);
  k_scan_blk<<<nb, 256, 0, stream>>>(DEG, ROWPTR, PART, N);
  k_scan_part<<<1, 64, 0, stream>>>(PART, nb);
  k_add_off<<<nb, 256, 0, stream>>>(ROWPTR, PART, N);
  hipMemcpyAsync(DEG, ROWPTR, (size_t)N * 4, hipMemcpyDeviceToDevice, stream);
  k_scatter<<<ebk, 256, 0, stream>>>(ei, DEG, COL, E, Etot);

  k_gemm1<<<gb, 256, 0, stream>>>(x, W1, as1, ad1, H1, A1S, A1D, N);
  k_agg1<<<AB, 256, 0, stream>>>(ROWPTR, COL, H1, A1S, A1D, b1, V1, ST1, N, NW);
  k_bnp<<<1, 128, 0, stream>>>(ST1, g1, be1, BNC1, N, 128);
  k_gemm2<<<gb, 256, 0, stream>>>(V1, W2, BNC1, as2, ad2, H2, A2S, A2D, N);
  k_agg2<<<AB, 256, 0, stream>>>(ROWPTR, COL, H2, A2S, A2D, b2, V2, ST2, N, NW);
  k_bnp<<<1, 128, 0, stream>>>(ST2, g2, be2, BNC2, N, 64);
  k_out<<<(N + 3) / 4, 256, 0, stream>>>(V2, BNC2, linW, linb, out, N);
}

// Round 4
// 323.482 us; speedup vs baseline: 3.0141x; 1.0985x over previous
//
#include <hip/hip_runtime.h>
#include <hip/hip_fp16.h>
#include <math.h>

#define LEAKY 0.2f

__device__ inline int h2i(__half2 h) { union { __half2 h; int i; } u; u.h = h; return u.i; }
__device__ inline __half2 i2h(int i) { union { __half2 h; int i; } u; u.i = i; return u.h; }

// ================= CSR build =================
__global__ __launch_bounds__(256) void k_hist(const int* __restrict__ ei,
                                              int* __restrict__ deg, int E, int Etot)
{
  int tid = blockIdx.x * 256 + threadIdx.x;
  if (tid >= Etot) return;
  int d = (tid < E) ? ei[E + tid] : tid - E;
  atomicAdd(&deg[d], 1);
}

__global__ __launch_bounds__(256) void k_scan_blk(const int* __restrict__ deg,
                                                  int* __restrict__ rowptr,
                                                  int* __restrict__ part, int N)
{
  __shared__ int ls[256];
  int t = threadIdx.x;
  int base = blockIdx.x * 1024 + t * 4;
  int d0 = (base     < N) ? deg[base]     : 0;
  int d1 = (base + 1 < N) ? deg[base + 1] : 0;
  int d2 = (base + 2 < N) ? deg[base + 2] : 0;
  int d3 = (base + 3 < N) ? deg[base + 3] : 0;
  int s = d0 + d1 + d2 + d3;
  ls[t] = s;
  __syncthreads();
  for (int off = 1; off < 256; off <<= 1) {
    int v = (t >= off) ? ls[t - off] : 0;
    __syncthreads();
    ls[t] += v;
    __syncthreads();
  }
  int excl = ls[t] - s;
  if (t == 255) part[blockIdx.x] = ls[255];
  if (base     <= N) rowptr[base]     = excl;
  if (base + 1 <= N) rowptr[base + 1] = excl + d0;
  if (base + 2 <= N) rowptr[base + 2] = excl + d0 + d1;
  if (base + 3 <= N) rowptr[base + 3] = excl + d0 + d1 + d2;
}

__global__ void k_scan_part(int* __restrict__ part, int nb)
{
  int lane = threadIdx.x;
  int v = (lane < nb) ? part[lane] : 0;
  int inc = v;
#pragma unroll
  for (int off = 1; off < 64; off <<= 1) {
    int u = __shfl_up(inc, off);
    if (lane >= off) inc += u;
  }
  if (lane < nb) part[lane] = inc - v;
}

__global__ __launch_bounds__(256) void k_add_off(int* __restrict__ rowptr,
                                                 const int* __restrict__ part,
                                                 int* __restrict__ cur, int N)
{
  int t = threadIdx.x;
  int base = blockIdx.x * 1024 + t * 4;
  int p = part[blockIdx.x];
#pragma unroll
  for (int k = 0; k < 4; ++k) {
    int i = base + k;
    if (i <= N) {
      int v = rowptr[i] + p;
      rowptr[i] = v;
      if (i < N) cur[i] = v;
    }
  }
}

__global__ __launch_bounds__(256) void k_scatter(const int* __restrict__ ei,
                                                 int* __restrict__ cur,
                                                 int* __restrict__ colx, int E, int Etot)
{
  int tid = blockIdx.x * 256 + threadIdx.x;
  if (tid >= Etot) return;
  int s, d;
  if (tid < E) { s = ei[tid]; d = ei[E + tid]; }
  else { s = d = tid - E; }
  int pos = atomicAdd(&cur[d], 1);
  colx[pos] = s;
}

// ================= GEMM1: h1 = x @ W1 (N x 128 @ 128 x 128), fp16 h1, fused att dots ======
__global__ __launch_bounds__(256) void k_gemm1(
    const float* __restrict__ x, const float* __restrict__ W,
    const float* __restrict__ att_s, const float* __restrict__ att_d,
    unsigned* __restrict__ h1h, float* __restrict__ a1s, float* __restrict__ a1d, int N)
{
  __shared__ float Wl[128][128];
  __shared__ float Xl[32][128];
  int t = threadIdx.x;
  const float4* W4 = (const float4*)W;
  float4* Wl4 = (float4*)&Wl[0][0];
#pragma unroll
  for (int i = 0; i < 16; ++i) Wl4[t + i * 256] = W4[t + i * 256];
  int row0 = blockIdx.x * 32;
  const float4* X4 = (const float4*)x;
  float4* Xl4 = (float4*)&Xl[0][0];
#pragma unroll
  for (int i = 0; i < 4; ++i) {
    int id = t + i * 256;
    int r = id >> 5, c = id & 31;
    int gr = row0 + r;
    Xl4[id] = (gr < N) ? X4[(size_t)gr * 32 + c] : make_float4(0.f, 0.f, 0.f, 0.f);
  }
  __syncthreads();
  int cg = t & 31, rg = t >> 5;
  float acc[4][4] = {};
  for (int k = 0; k < 128; k += 4) {
    float4 xv[4];
#pragma unroll
    for (int r = 0; r < 4; ++r) xv[r] = *(const float4*)&Xl[rg * 4 + r][k];
#pragma unroll
    for (int kk = 0; kk < 4; ++kk) {
      float4 wv = *(const float4*)&Wl[k + kk][cg * 4];
#pragma unroll
      for (int r = 0; r < 4; ++r) {
        float xs = (&xv[r].x)[kk];
        acc[r][0] = fmaf(xs, wv.x, acc[r][0]);
        acc[r][1] = fmaf(xs, wv.y, acc[r][1]);
        acc[r][2] = fmaf(xs, wv.z, acc[r][2]);
        acc[r][3] = fmaf(xs, wv.w, acc[r][3]);
      }
    }
  }
  int col = cg * 4;
  int h = (t >> 4) & 1;
  float4 asv = *(const float4*)&att_s[col];
  float4 adv = *(const float4*)&att_d[col];
#pragma unroll
  for (int r = 0; r < 4; ++r) {
    int gr = row0 + rg * 4 + r;
    float ps = acc[r][0] * asv.x + acc[r][1] * asv.y + acc[r][2] * asv.z + acc[r][3] * asv.w;
    float pd = acc[r][0] * adv.x + acc[r][1] * adv.y + acc[r][2] * adv.z + acc[r][3] * adv.w;
    ps += __shfl_xor(ps, 1); ps += __shfl_xor(ps, 2); ps += __shfl_xor(ps, 4); ps += __shfl_xor(ps, 8);
    pd += __shfl_xor(pd, 1); pd += __shfl_xor(pd, 2); pd += __shfl_xor(pd, 4); pd += __shfl_xor(pd, 8);
    if (gr < N) {
      unsigned p01 = (unsigned)h2i(__floats2half2_rn(acc[r][0], acc[r][1]));
      unsigned p23 = (unsigned)h2i(__floats2half2_rn(acc[r][2], acc[r][3]));
      *(uint2*)&h1h[(size_t)gr * 64 + cg * 2] = make_uint2(p01, p23);
      if ((t & 15) == 0) { a1s[gr * 2 + h] = ps; a1d[gr * 2 + h] = pd; }
    }
  }
}

// ================= Aggregate layer 1: wave per node, fp16 gather, 8x in-flight ============
__global__ __launch_bounds__(256) void k_agg1(
    const int* __restrict__ rowptr, const int* __restrict__ colx,
    const unsigned* __restrict__ h1h, const float* __restrict__ a1s,
    const float* __restrict__ a1d, const float* __restrict__ b1,
    float* __restrict__ v1, float* __restrict__ stats, int N, int NW)
{
  int t = threadIdx.x;
  int lane = t & 63;
  int w = t >> 6;
  int gw = blockIdx.x * 4 + w;
  bool hi = lane >= 32;
  float2 bias = *(const float2*)&b1[lane * 2];
  float bns0 = 0.f, bns1 = 0.f, bnq0 = 0.f, bnq1 = 0.f;
  for (int n = gw; n < N; n += NW) {
    float2 ad = *(const float2*)&a1d[n * 2];
    int start = rowptr[n], end = rowptr[n + 1];
    float se = 0.f;
    float2 acc = make_float2(0.f, 0.f);
    for (int base = start; base < end; base += 64) {
      int cnt = end - base; if (cnt > 64) cnt = 64;
      int sl = 0; int epk = 0;
      if (lane < cnt) {
        sl = colx[base + lane];
        float2 av = *(const float2*)&a1s[sl * 2];
        float x0 = av.x + ad.x, x1 = av.y + ad.y;
        x0 = (x0 > 0.f) ? x0 : LEAKY * x0;
        x1 = (x1 > 0.f) ? x1 : LEAKY * x1;
        epk = h2i(__floats2half2_rn(__expf(x0), __expf(x1)));
      }
      int j = 0, lim = cnt & ~7;
      for (; j < lim; j += 8) {
        int ss[8], ee[8];
#pragma unroll
        for (int k = 0; k < 8; ++k) { ss[k] = __shfl(sl, j + k); ee[k] = __shfl(epk, j + k); }
        unsigned rr[8];
#pragma unroll
        for (int k = 0; k < 8; ++k) rr[k] = h1h[(size_t)ss[k] * 64 + lane];
#pragma unroll
        for (int k = 0; k < 8; ++k) {
          float2 ef = __half22float2(i2h(ee[k]));
          float wg = hi ? ef.y : ef.x;
          float2 rf = __half22float2(i2h((int)rr[k]));
          se += wg;
          acc.x = fmaf(wg, rf.x, acc.x);
          acc.y = fmaf(wg, rf.y, acc.y);
        }
      }
      for (; j < cnt; ++j) {
        int s0 = __shfl(sl, j);
        int e0 = __shfl(epk, j);
        float2 ef = __half22float2(i2h(e0));
        float wg = hi ? ef.y : ef.x;
        float2 rf = __half22float2(i2h((int)h1h[(size_t)s0 * 64 + lane]));
        se += wg;
        acc.x = fmaf(wg, rf.x, acc.x);
        acc.y = fmaf(wg, rf.y, acc.y);
      }
    }
    float inv = 1.f / se;
    float2 o;
    o.x = acc.x * inv + bias.x;
    o.y = acc.y * inv + bias.y;
    *(float2*)&v1[(size_t)n * 128 + lane * 2] = o;
    bns0 += o.x; bnq0 += o.x * o.x;
    bns1 += o.y; bnq1 += o.y * o.y;
  }
  __shared__ float reds[4][128], redq[4][128];
  reds[w][lane * 2] = bns0; reds[w][lane * 2 + 1] = bns1;
  redq[w][lane * 2] = bnq0; redq[w][lane * 2 + 1] = bnq1;
  __syncthreads();
  if (t < 128) {
    atomicAdd(&stats[t],       reds[0][t] + reds[1][t] + reds[2][t] + reds[3][t]);
    atomicAdd(&stats[128 + t], redq[0][t] + redq[1][t] + redq[2][t] + redq[3][t]);
  }
}

// ================= BN params =================
__global__ void k_bnp(const float* __restrict__ stats, const float* __restrict__ g,
                      const float* __restrict__ be, float* __restrict__ bnc, int N, int F)
{
  int f = threadIdx.x;
  if (f < F) {
    float mu = stats[f] / (float)N;
    float var = stats[F + f] / (float)N - mu * mu;
    float k = g[f] * rsqrtf(var + 1e-5f);
    bnc[f] = k;
    bnc[F + f] = be[f] - mu * k;
  }
}

// ================= GEMM2: h2 = relu(bn(v1)) @ W2 (N x 128 @ 128 x 64), fp16 h2 =============
__global__ __launch_bounds__(256) void k_gemm2(
    const float* __restrict__ v1, const float* __restrict__ W2,
    const float* __restrict__ bnc1,
    const float* __restrict__ att_s, const float* __restrict__ att_d,
    unsigned* __restrict__ h2h, float* __restrict__ a2s, float* __restrict__ a2d, int N)
{
  __shared__ float Wl[128][64];
  __shared__ float Xl[32][128];
  __shared__ float kc[128], sc[128];
  int t = threadIdx.x;
  if (t < 128) { kc[t] = bnc1[t]; sc[t] = bnc1[128 + t]; }
  __syncthreads();
  const float4* W4 = (const float4*)W2;
  float4* Wl4 = (float4*)&Wl[0][0];
#pragma unroll
  for (int i = 0; i < 8; ++i) Wl4[t + i * 256] = W4[t + i * 256];
  int row0 = blockIdx.x * 32;
  float4* Xl4 = (float4*)&Xl[0][0];
#pragma unroll
  for (int i = 0; i < 4; ++i) {
    int id = t + i * 256;
    int r = id >> 5, c4 = id & 31;
    int gr = row0 + r;
    float4 v = (gr < N) ? *(const float4*)&v1[(size_t)gr * 128 + c4 * 4]
                        : make_float4(0.f, 0.f, 0.f, 0.f);
    int f0 = c4 * 4;
    float4 o;
    o.x = fmaxf(v.x * kc[f0]     + sc[f0],     0.f);
    o.y = fmaxf(v.y * kc[f0 + 1] + sc[f0 + 1], 0.f);
    o.z = fmaxf(v.z * kc[f0 + 2] + sc[f0 + 2], 0.f);
    o.w = fmaxf(v.w * kc[f0 + 3] + sc[f0 + 3], 0.f);
    Xl4[id] = o;
  }
  __syncthreads();
  int cg = t & 15, rg = t >> 4;
  float acc[2][4] = {};
  for (int k = 0; k < 128; k += 4) {
    float4 xv0 = *(const float4*)&Xl[rg * 2][k];
    float4 xv1 = *(const float4*)&Xl[rg * 2 + 1][k];
#pragma unroll
    for (int kk = 0; kk < 4; ++kk) {
      float4 wv = *(const float4*)&Wl[k + kk][cg * 4];
      float x0 = (&xv0.x)[kk];
      float x1 = (&xv1.x)[kk];
      acc[0][0] = fmaf(x0, wv.x, acc[0][0]);
      acc[0][1] = fmaf(x0, wv.y, acc[0][1]);
      acc[0][2] = fmaf(x0, wv.z, acc[0][2]);
      acc[0][3] = fmaf(x0, wv.w, acc[0][3]);
      acc[1][0] = fmaf(x1, wv.x, acc[1][0]);
      acc[1][1] = fmaf(x1, wv.y, acc[1][1]);
      acc[1][2] = fmaf(x1, wv.z, acc[1][2]);
      acc[1][3] = fmaf(x1, wv.w, acc[1][3]);
    }
  }
  int col = cg * 4;
  float4 asv = *(const float4*)&att_s[col];
  float4 adv = *(const float4*)&att_d[col];
#pragma unroll
  for (int r = 0; r < 2; ++r) {
    int gr = row0 + rg * 2 + r;
    float ps = acc[r][0] * asv.x + acc[r][1] * asv.y + acc[r][2] * asv.z + acc[r][3] * asv.w;
    float pd = acc[r][0] * adv.x + acc[r][1] * adv.y + acc[r][2] * adv.z + acc[r][3] * adv.w;
    ps += __shfl_xor(ps, 1); ps += __shfl_xor(ps, 2); ps += __shfl_xor(ps, 4); ps += __shfl_xor(ps, 8);
    pd += __shfl_xor(pd, 1); pd += __shfl_xor(pd, 2); pd += __shfl_xor(pd, 4); pd += __shfl_xor(pd, 8);
    if (gr < N) {
      unsigned p01 = (unsigned)h2i(__floats2half2_rn(acc[r][0], acc[r][1]));
      unsigned p23 = (unsigned)h2i(__floats2half2_rn(acc[r][2], acc[r][3]));
      *(uint2*)&h2h[(size_t)gr * 32 + cg * 2] = make_uint2(p01, p23);
      if ((t & 15) == 0) { a2s[gr] = ps; a2d[gr] = pd; }
    }
  }
}

// ================= Aggregate layer 2: wave per node, fp16 gather, 8x in-flight =============
__global__ __launch_bounds__(256) void k_agg2(
    const int* __restrict__ rowptr, const int* __restrict__ colx,
    const __half* __restrict__ h2h, const float* __restrict__ a2s,
    const float* __restrict__ a2d, const float* __restrict__ b2,
    float* __restrict__ v2, float* __restrict__ stats, int N, int NW)
{
  int t = threadIdx.x;
  int lane = t & 63;
  int w = t >> 6;
  int gw = blockIdx.x * 4 + w;
  float bias = b2[lane];
  float bns = 0.f, bnq = 0.f;
  for (int n = gw; n < N; n += NW) {
    float ad = a2d[n];
    int start = rowptr[n], end = rowptr[n + 1];
    float se = 0.f, acc = 0.f;
    for (int base = start; base < end; base += 64) {
      int cnt = end - base; if (cnt > 64) cnt = 64;
      int sl = 0; float ev = 0.f;
      if (lane < cnt) {
        sl = colx[base + lane];
        float av = a2s[sl] + ad;
        av = (av > 0.f) ? av : LEAKY * av;
        ev = __expf(av);
      }
      int j = 0, lim = cnt & ~7;
      for (; j < lim; j += 8) {
        int ss[8]; float ee[8];
#pragma unroll
        for (int k = 0; k < 8; ++k) { ss[k] = __shfl(sl, j + k); ee[k] = __shfl(ev, j + k); }
        __half rr[8];
#pragma unroll
        for (int k = 0; k < 8; ++k) rr[k] = h2h[(size_t)ss[k] * 64 + lane];
#pragma unroll
        for (int k = 0; k < 8; ++k) {
          se += ee[k];
          acc = fmaf(ee[k], __half2float(rr[k]), acc);
        }
      }
      for (; j < cnt; ++j) {
        int s0 = __shfl(sl, j);
        float e0 = __shfl(ev, j);
        se += e0;
        acc = fmaf(e0, __half2float(h2h[(size_t)s0 * 64 + lane]), acc);
      }
    }
    float outv = acc / se + bias;
    v2[(size_t)n * 64 + lane] = outv;
    bns += outv; bnq += outv * outv;
  }
  __shared__ float reds[4][64], redq[4][64];
  reds[w][lane] = bns; redq[w][lane] = bnq;
  __syncthreads();
  if (t < 64) {
    atomicAdd(&stats[t],      reds[0][t] + reds[1][t] + reds[2][t] + reds[3][t]);
    atomicAdd(&stats[64 + t], redq[0][t] + redq[1][t] + redq[2][t] + redq[3][t]);
  }
}

// ================= Final: out = relu(bn(v2)) @ linW + linb =================
__global__ __launch_bounds__(256) void k_out(
    const float* __restrict__ v2, const float* __restrict__ bnc2,
    const float* __restrict__ linW, const float* __restrict__ linb,
    float* __restrict__ out, int N)
{
  int lane = threadIdx.x & 63;
  int n = blockIdx.x * 4 + (threadIdx.x >> 6);
  if (n >= N) return;
  float v = v2[(size_t)n * 64 + lane];
  float hn = fmaxf(v * bnc2[lane] + bnc2[64 + lane], 0.f);
  float p = hn * linW[lane];
#pragma unroll
  for (int off = 32; off; off >>= 1) p += __shfl_xor(p, off);
  if (lane == 0) out[n] = p + linb[0];
}

extern "C" void kernel_launch(void* const* d_in, const int* in_sizes, int n_in,
                              void* d_out, int out_size, void* d_ws, size_t ws_size,
                              hipStream_t stream)
{
  const float* x    = (const float*)d_in[0];
  const int*   ei   = (const int*)d_in[1];
  const float* W1   = (const float*)d_in[2];
  const float* as1  = (const float*)d_in[3];
  const float* ad1  = (const float*)d_in[4];
  const float* b1   = (const float*)d_in[5];
  const float* g1   = (const float*)d_in[6];
  const float* be1  = (const float*)d_in[7];
  const float* W2   = (const float*)d_in[8];
  const float* as2  = (const float*)d_in[9];
  const float* ad2  = (const float*)d_in[10];
  const float* b2   = (const float*)d_in[11];
  const float* g2   = (const float*)d_in[12];
  const float* be2  = (const float*)d_in[13];
  const float* linW = (const float*)d_in[14];
  const float* linb = (const float*)d_in[15];
  float* out = (float*)d_out;

  int N = in_sizes[0] / 128;
  int E = in_sizes[1] / 2;
  int Etot = E + N;

  float* ws = (float*)d_ws;
  size_t o = 0;
  float* H1HF = ws + o; o += (size_t)N * 64;   // N*128 halves (layer1 h, fp16)
  float* V1   = ws + o; o += (size_t)N * 128;
  float* A1S  = ws + o; o += (size_t)N * 2;
  float* A1D  = ws + o; o += (size_t)N * 2;
  float* A2S  = ws + o; o += N;
  float* A2D  = ws + o; o += N;
  float* ST1  = ws + o; o += 256;              // zero-region start
  float* ST2  = ws + o; o += 128;              // zero-region end (384 floats)
  float* BNC1 = ws + o; o += 256;
  float* BNC2 = ws + o; o += 128;
  int* ROWPTR = (int*)(ws + o); o += (size_t)N + 1;
  int* COL    = (int*)(ws + o); o += (size_t)Etot;
  int* DEG    = (int*)(ws + o); o += N;        // scatter cursor
  int* PART   = (int*)(ws + o); o += 64;
  unsigned* H1H = (unsigned*)H1HF;
  unsigned* H2H = (unsigned*)H1HF;             // layer-2 h aliases dead H1 region (needs N*32)
  float* V2 = V1;                              // v2 aliases dead V1 region (needs N*64)

  hipMemsetAsync(ST1, 0, 384 * 4, stream);
  hipMemsetAsync(DEG, 0, (size_t)N * 4, stream);

  int ebk = (Etot + 255) / 256;
  int nb = (N + 1024) / 1024;
  int gb = (N + 31) / 32;
  const int AB = 2048;               // 8192 waves (full residency)
  const int NW = AB * 4;

  k_hist<<<ebk, 256, 0, stream>>>(ei, DEG, E, Etot);
  k_scan_blk<<<nb, 256, 0, stream>>>(DEG, ROWPTR, PART, N);
  k_scan_part<<<1, 64, 0, stream>>>(PART, nb);
  k_add_off<<<nb, 256, 0, stream>>>(ROWPTR, PART, DEG, N);
  k_scatter<<<ebk, 256, 0, stream>>>(ei, DEG, COL, E, Etot);

  k_gemm1<<<gb, 256, 0, stream>>>(x, W1, as1, ad1, H1H, A1S, A1D, N);
  k_agg1<<<AB, 256, 0, stream>>>(ROWPTR, COL, H1H, A1S, A1D, b1, V1, ST1, N, NW);
  k_bnp<<<1, 128, 0, stream>>>(ST1, g1, be1, BNC1, N, 128);
  k_gemm2<<<gb, 256, 0, stream>>>(V1, W2, BNC1, as2, ad2, H2H, A2S, A2D, N);
  k_agg2<<<AB, 256, 0, stream>>>(ROWPTR, COL, (const __half*)H2H, A2S, A2D, b2, V2, ST2, N, NW);
  k_bnp<<<1, 128, 0, stream>>>(ST2, g2, be2, BNC2, N, 64);
  k_out<<<(N + 3) / 4, 256, 0, stream>>>(V2, BNC2, linW, linb, out, N);
}